// Round 2
// baseline (374.362 us; speedup 1.0000x reference)
//
#include <hip/hip_runtime.h>
#include <stdint.h>

#define BATCH 256
#define CIN   64
#define LIN   4096
#define PADN  3
#define LPAD  (LIN + 2*PADN)   /* 4102 */
#define COUT  128
#define KW    7
#define LPOOL 2048
#define JCO   8                 /* output channels per conv block */
#define ZWORDS 65               /* ceil(4102/64) */
#define NPERCH (256LL * 2048LL)

typedef unsigned long long u64;

// ---------------------------------------------------------------------------
// pack_x: fp32 (B,64,4096) -> sign word per padded position (bit c = ch c >0),
// nonzero word to zx (slow path only), and zbits bit set if position contains
// an exact 0.0 (rare). Padding value -1 -> sign 0, nonzero all-ones.
// ---------------------------------------------------------------------------
__global__ __launch_bounds__(256) void pack_x_kernel(const float* __restrict__ x,
                                                     u64* __restrict__ sx,
                                                     u64* __restrict__ zx,
                                                     u64* __restrict__ zbits)
{
    int pos = blockIdx.x * 256 + threadIdx.x;
    int b   = blockIdx.y;
    if (pos >= LPAD) return;
    u64 s = 0, z = 0;
    int lx = pos - PADN;
    if (lx < 0 || lx >= LIN) {
        s = 0;        // -1 not > 0
        z = ~0ull;    // -1 != 0
    } else {
        const float* xb = x + (size_t)b * CIN * LIN + lx;
        #pragma unroll
        for (int c = 0; c < CIN; ++c) {
            float v = xb[(size_t)c * LIN];
            s |= ((u64)(v > 0.0f))  << c;
            z |= ((u64)(v != 0.0f)) << c;
        }
    }
    sx[(size_t)b * LPAD + pos] = s;
    zx[(size_t)b * LPAD + pos] = z;
    if (z != ~0ull)
        atomicOr(&zbits[(size_t)b * ZWORDS + (pos >> 6)], 1ull << (pos & 63));
}

// ---------------------------------------------------------------------------
// pack_w: (128,64,7) -> sign/nonzero words; wflag set if any W element == 0.
// ---------------------------------------------------------------------------
__global__ void pack_w_kernel(const float* __restrict__ w,
                              ulonglong2* __restrict__ pw,
                              unsigned int* __restrict__ wflag)
{
    int t = blockIdx.x * blockDim.x + threadIdx.x;
    if (t >= COUT * KW) return;
    int co = t / KW, k = t % KW;
    u64 s = 0, z = 0;
    for (int c = 0; c < CIN; ++c) {
        float v = w[((size_t)co * CIN + c) * KW + k];
        s |= ((u64)(v > 0.0f))  << c;
        z |= ((u64)(v != 0.0f)) << c;
    }
    pw[t] = make_ulonglong2(s, z);
    if (z != ~0ull) atomicOr(wflag, 1u);
}

// ---------------------------------------------------------------------------
// Exact (zero-aware) pooled value for one (co, lp): max of the two signed dots.
// ---------------------------------------------------------------------------
__device__ __forceinline__ int conv_pooled_exact(const u64 w8s[8],
                                                 const u64* __restrict__ zrow,
                                                 int bpos,
                                                 const ulonglong2* __restrict__ wj)
{
    u64 w8z[8];
    #pragma unroll
    for (int t = 0; t < 8; ++t) w8z[t] = zrow[bpos + t];
    int d0 = 0, d1 = 0;
    #pragma unroll
    for (int k = 0; k < KW; ++k) {
        u64 wsk = wj[k].x, wzk = wj[k].y;
        u64 m0 = w8z[k]     & wzk;
        u64 m1 = w8z[k + 1] & wzk;
        d0 += __popcll(m0) - 2 * __popcll((w8s[k]     ^ wsk) & m0);
        d1 += __popcll(m1) - 2 * __popcll((w8s[k + 1] ^ wsk) & m1);
    }
    return (d0 > d1) ? d0 : d1;
}

// ---------------------------------------------------------------------------
// Core per-thread-iteration: returns p[JCO] pooled pre-PReLU ints.
// Window sign words come from LDS; weights from global (wave-uniform ->
// scalar loads); slow path (rare) reads z-words from global.
// ---------------------------------------------------------------------------
__device__ __forceinline__ void conv_group(const u64* __restrict__ sxs,
                                           const u64* __restrict__ zbs,
                                           const u64* __restrict__ zrow,
                                           const ulonglong2* __restrict__ pw,
                                           int co0, int lp, unsigned wbad,
                                           int p[JCO])
{
    const int bpos = 2 * lp;
    u64 w8[8];
    const u64* wp = sxs + bpos;
    #pragma unroll
    for (int t = 0; t < 8; ++t) w8[t] = wp[t];

    // 8-bit zero summary for positions bpos..bpos+7
    int wi = bpos >> 6, sh = bpos & 63;
    u64 zlo = zbs[wi], zhi = zbs[wi + 1];
    unsigned zm = (unsigned)(((zlo >> sh) | ((zhi << 1) << (63 - sh))) & 0xFFull);

    if ((zm | wbad) == 0) {
        #pragma unroll
        for (int j = 0; j < JCO; ++j) {
            const ulonglong2* wj = pw + (size_t)(co0 + j) * KW;
            int c0 = 0, c1 = 0;
            #pragma unroll
            for (int k = 0; k < KW; ++k) {
                u64 wsk = wj[k].x;
                c0 += __popcll(w8[k]     ^ wsk);
                c1 += __popcll(w8[k + 1] ^ wsk);
            }
            int m = (c0 < c1) ? c0 : c1;
            p[j] = (CIN * KW) - 2 * m;
        }
    } else {
        #pragma unroll 1
        for (int j = 0; j < JCO; ++j)
            p[j] = conv_pooled_exact(w8, zrow, bpos, pw + (size_t)(co0 + j) * KW);
    }
}

// ---------------------------------------------------------------------------
// Pass A: conv+pool+PReLU-split integer stats. Block = (co-group of 8, b).
// ---------------------------------------------------------------------------
__global__ __launch_bounds__(256) void conv_stats_kernel(
    const u64* __restrict__ sx, const u64* __restrict__ zx,
    const u64* __restrict__ zbits, const ulonglong2* __restrict__ pw,
    const unsigned int* __restrict__ wflag, unsigned long long* __restrict__ stats)
{
    __shared__ __align__(16) u64 sxs[LPAD];
    __shared__ u64 zbs[ZWORDS + 1];
    __shared__ int redu[4][32];

    const int tid = threadIdx.x;
    const int co0 = blockIdx.x * JCO;
    const int b   = blockIdx.y;
    const unsigned wbad = *wflag;

    const u64* srow = sx + (size_t)b * LPAD;
    for (int i = tid; i < LPAD; i += 256) sxs[i] = srow[i];
    if (tid < ZWORDS) zbs[tid] = zbits[(size_t)b * ZWORDS + tid];
    if (tid == ZWORDS) zbs[ZWORDS] = 0;
    __syncthreads();

    const u64* zrow = zx + (size_t)b * LPAD;

    int sp[JCO], sn[JCO], qp[JCO], qn[JCO];
    #pragma unroll
    for (int j = 0; j < JCO; ++j) { sp[j]=0; sn[j]=0; qp[j]=0; qn[j]=0; }

    for (int i = 0; i < 8; ++i) {
        int lp = i * 256 + tid;
        int p[JCO];
        conv_group(sxs, zbs, zrow, pw, co0, lp, wbad, p);
        #pragma unroll
        for (int j = 0; j < JCO; ++j) {
            int pp = p[j];
            bool pos = pp > 0;
            int p2 = pp * pp;
            sp[j] += pos ? pp : 0;
            sn[j] += pos ? 0  : pp;
            qp[j] += pos ? p2 : 0;
            qn[j] += pos ? 0  : p2;
        }
    }

    int vals[32];
    #pragma unroll
    for (int j = 0; j < JCO; ++j) {
        vals[j*4+0] = sp[j]; vals[j*4+1] = sn[j];
        vals[j*4+2] = qp[j]; vals[j*4+3] = qn[j];
    }
    #pragma unroll
    for (int v = 0; v < 32; ++v)
        #pragma unroll
        for (int off = 32; off >= 1; off >>= 1)
            vals[v] += __shfl_down(vals[v], off, 64);

    int wid = tid >> 6, lane = tid & 63;
    if (lane == 0) {
        #pragma unroll
        for (int v = 0; v < 32; ++v) redu[wid][v] = vals[v];
    }
    __syncthreads();
    if (tid < 32) {
        int s = redu[0][tid] + redu[1][tid] + redu[2][tid] + redu[3][tid];
        int j = tid >> 2, si = tid & 3;
        atomicAdd(&stats[(size_t)(co0 + j) * 4 + si],
                  (unsigned long long)(long long)s);
    }
}

// ---------------------------------------------------------------------------
// finalize: exact integer sums -> per-channel BN scale/shift (double math).
// ---------------------------------------------------------------------------
__global__ void finalize_kernel(const unsigned long long* __restrict__ stats,
                                const float* __restrict__ alpha,
                                const float* __restrict__ gamma,
                                const float* __restrict__ beta,
                                float2* __restrict__ scsh)
{
    int c = threadIdx.x;
    if (c >= COUT) return;
    long long sp = (long long)stats[c*4+0];
    long long sn = (long long)stats[c*4+1];
    long long qp = (long long)stats[c*4+2];
    long long qn = (long long)stats[c*4+3];
    double a   = (double)alpha[0];
    double N   = (double)NPERCH;
    double sum = (double)sp + a * (double)sn;
    double ssq = (double)qp + a * a * (double)qn;
    double mean = sum / N;
    double var  = ssq / N - mean * mean;
    double inv  = 1.0 / sqrt(var + 1e-5);
    double g    = (double)gamma[c];
    scsh[c] = make_float2((float)(g * inv),
                          (float)((double)beta[c] - mean * g * inv));
}

// ---------------------------------------------------------------------------
// Pass B: conv+pool+PReLU+BN affine, fp32 out. Same block structure.
// ---------------------------------------------------------------------------
__global__ __launch_bounds__(256) void conv_write_kernel(
    const u64* __restrict__ sx, const u64* __restrict__ zx,
    const u64* __restrict__ zbits, const ulonglong2* __restrict__ pw,
    const unsigned int* __restrict__ wflag, const float2* __restrict__ scsh,
    const float* __restrict__ alpha, float* __restrict__ out)
{
    __shared__ __align__(16) u64 sxs[LPAD];
    __shared__ u64 zbs[ZWORDS + 1];

    const int tid = threadIdx.x;
    const int co0 = blockIdx.x * JCO;
    const int b   = blockIdx.y;
    const unsigned wbad = *wflag;
    const float a = alpha[0];

    const u64* srow = sx + (size_t)b * LPAD;
    for (int i = tid; i < LPAD; i += 256) sxs[i] = srow[i];
    if (tid < ZWORDS) zbs[tid] = zbits[(size_t)b * ZWORDS + tid];
    if (tid == ZWORDS) zbs[ZWORDS] = 0;
    __syncthreads();

    const u64* zrow = zx + (size_t)b * LPAD;

    float2 ss[JCO];
    #pragma unroll
    for (int j = 0; j < JCO; ++j) ss[j] = scsh[co0 + j];

    for (int i = 0; i < 8; ++i) {
        int lp = i * 256 + tid;
        int p[JCO];
        conv_group(sxs, zbs, zrow, pw, co0, lp, wbad, p);
        #pragma unroll
        for (int j = 0; j < JCO; ++j) {
            int pp = p[j];
            float yf = (pp > 0) ? (float)pp : a * (float)pp;
            out[((size_t)b * COUT + co0 + j) * LPOOL + lp] =
                fmaf(yf, ss[j].x, ss[j].y);
        }
    }
}

// ---------------------------------------------------------------------------
extern "C" void kernel_launch(void* const* d_in, const int* in_sizes, int n_in,
                              void* d_out, int out_size, void* d_ws, size_t ws_size,
                              hipStream_t stream)
{
    const float* x     = (const float*)d_in[0];
    const float* W     = (const float*)d_in[1];
    const float* alpha = (const float*)d_in[2];
    const float* gamma = (const float*)d_in[3];
    const float* beta  = (const float*)d_in[4];
    float* out = (float*)d_out;

    char* ws = (char*)d_ws;
    size_t off = 0;
    u64* sxw = (u64*)(ws + off);        off += (size_t)BATCH * LPAD * 8;
    u64* zxw = (u64*)(ws + off);        off += (size_t)BATCH * LPAD * 8;
    ulonglong2* pw = (ulonglong2*)(ws + off); off += (size_t)COUT * KW * 16;
    float2* scsh = (float2*)(ws + off); off += (size_t)COUT * 8;
    // zeroed region: stats | wflag | zbits (contiguous, one memset)
    unsigned long long* stats = (unsigned long long*)(ws + off);
    size_t zoff = off;                  off += (size_t)COUT * 4 * 8;
    unsigned int* wflag = (unsigned int*)(ws + off); off += 16;
    u64* zbits = (u64*)(ws + off);      off += (size_t)BATCH * ZWORDS * 8;

    hipMemsetAsync(ws + zoff, 0, off - zoff, stream);

    pack_x_kernel<<<dim3((LPAD + 255) / 256, BATCH), 256, 0, stream>>>(x, sxw, zxw, zbits);
    pack_w_kernel<<<dim3(4), 256, 0, stream>>>(W, pw, wflag);
    conv_stats_kernel<<<dim3(COUT / JCO, BATCH), 256, 0, stream>>>(sxw, zxw, zbits, pw, wflag, stats);
    finalize_kernel<<<dim3(1), 128, 0, stream>>>(stats, alpha, gamma, beta, scsh);
    conv_write_kernel<<<dim3(COUT / JCO, BATCH), 256, 0, stream>>>(sxw, zxw, zbits, pw, wflag, scsh, alpha, out);
}